// Round 1
// baseline (223.462 us; speedup 1.0000x reference)
//
#include <hip/hip_runtime.h>
#include <math.h>

// Stickbreaking attention, fp32, flash-style with suffix-scan carry.
// B=2 H=16 S=1024 D=64.  out[i,:] = sum_{k<=i} z[i,k]*exp(sum_{j=k..i} lb[i,j]) * v[k,:]
//   z = sigmoid(l), lb = -softplus(l), l = q.k/8
// Iterate key tiles RIGHT-TO-LEFT carrying C[i] = sum of lb over tiles already done
// (all j > current tile). Within tile: suffix scan via registers + 16-lane shfl.

#define S_LEN 1024
#define D_DIM 64
#define LDSS 68   // 64 + 4 pad: keeps float4 alignment, breaks pow-2 bank strides

#define UNPACK4(dst, src) { dst[0]=(src).x; dst[1]=(src).y; dst[2]=(src).z; dst[3]=(src).w; }

__global__ __launch_bounds__(256, 2) void stickbreak_kernel(
    const float* __restrict__ Qg, const float* __restrict__ Kg,
    const float* __restrict__ Vg, float* __restrict__ Og)
{
    const int t  = threadIdx.x;
    const int n  = blockIdx.x;       // 0..511
    const int bh = n >> 4;           // 0..31
    const int x  = n & 15;
    // complementary heavy/light pairing across the two dispatch rounds (512 blocks / 256 CUs)
    const int qt = (bh & 16) ? (15 - x) : x;

    const size_t hbase = (size_t)bh * S_LEN * D_DIM;
    const float* q = Qg + hbase + (size_t)qt * 64 * D_DIM;
    const float* k = Kg + hbase;
    const float* v = Vg + hbase;
    float*       o = Og + hbase + (size_t)qt * 64 * D_DIM;

    __shared__ float Qs[64][LDSS];   // Q^T: Qs[d][i]
    __shared__ float Vs[64][LDSS];   // V  : Vs[j][d]
    __shared__ float KWs[64][LDSS];  // K^T (Ks[d][j]) during GEMM1, then W (Ws[i][j])

    const int r4 = t >> 4;           // 0..15 (staging row group)
    const int c4 = t & 15;           // 0..15 (staging float4 col)
    const int ti = t >> 4;           // fragment row group -> i0
    const int tj = t & 15;           // fragment col group -> j0 (and d0 in GEMM2)
    const int i0 = ti * 4;
    const int j0 = tj * 4;
    const int lane = t & 63;
    const int grp0 = lane & 48;      // first lane of this 16-lane scan group

    // ---- stage Q transposed (once) ----
    #pragma unroll
    for (int ch = 0; ch < 4; ++ch) {
        const int row = r4 + 16 * ch;
        const float4 qv = *(const float4*)(q + row * D_DIM + 4 * c4);
        Qs[4*c4+0][row] = qv.x;
        Qs[4*c4+1][row] = qv.y;
        Qs[4*c4+2][row] = qv.z;
        Qs[4*c4+3][row] = qv.w;
    }

    float Of[4][4] = {};
    float Crow[4] = {0.f, 0.f, 0.f, 0.f};   // carried sum of lb over tiles right of current

    for (int kt = qt; kt >= 0; --kt) {
        __syncthreads();   // prev iter done reading Vs/KWs
        // ---- stage K (transposed) and V (natural) ----
        const float* kp = k + (size_t)kt * 64 * D_DIM;
        const float* vp = v + (size_t)kt * 64 * D_DIM;
        #pragma unroll
        for (int ch = 0; ch < 4; ++ch) {
            const int row = r4 + 16 * ch;
            const float4 kv = *(const float4*)(kp + row * D_DIM + 4 * c4);
            KWs[4*c4+0][row] = kv.x;
            KWs[4*c4+1][row] = kv.y;
            KWs[4*c4+2][row] = kv.z;
            KWs[4*c4+3][row] = kv.w;
            const float4 vv = *(const float4*)(vp + row * D_DIM + 4 * c4);
            *(float4*)&Vs[row][4*c4] = vv;
        }
        __syncthreads();

        // ---- GEMM1: S = Q K^T  (4x4 frag per thread) ----
        float acc[4][4] = {};
        #pragma unroll 8
        for (int d = 0; d < 64; ++d) {
            const float4 av = *(const float4*)&Qs[d][i0];
            const float4 bv = *(const float4*)&KWs[d][j0];
            float a[4], b[4];
            UNPACK4(a, av);
            UNPACK4(b, bv);
            #pragma unroll
            for (int r = 0; r < 4; ++r)
                #pragma unroll
                for (int c = 0; c < 4; ++c)
                    acc[r][c] = fmaf(a[r], b[c], acc[r][c]);
        }

        // ---- z, log_beta, causal mask on diagonal tile ----
        const bool diag = (kt == qt);
        float zf[4][4], lb[4][4];
        #pragma unroll
        for (int r = 0; r < 4; ++r) {
            #pragma unroll
            for (int c = 0; c < 4; ++c) {
                const float l   = acc[r][c] * 0.125f;
                const float e   = __expf(-fabsf(l));          // exp(-|l|)
                const float inv = 1.0f / (1.0f + e);
                const float zc  = (l >= 0.f) ? inv : e * inv; // sigmoid(l)
                const float lbc = -(fmaxf(l, 0.f) + __logf(1.0f + e)); // -softplus(l)
                const bool masked = diag && (j0 + c > i0 + r);
                zf[r][c] = masked ? 0.f : zc;
                lb[r][c] = masked ? 0.f : lbc;
            }
        }

        __syncthreads();   // all GEMM1 reads of KWs done before overwriting with W

        // ---- suffix scan along j + weights; write W into KWs ----
        #pragma unroll
        for (int r = 0; r < 4; ++r) {
            const float s3 = lb[r][3];
            const float s2 = lb[r][2] + s3;
            const float s1 = lb[r][1] + s2;
            const float s0 = lb[r][0] + s1;   // this thread's group total
            float g = s0;                      // inclusive suffix over 16 groups
            #pragma unroll
            for (int off = 1; off < 16; off <<= 1) {
                const float gg = __shfl_down(g, off, 64);
                if (tj + off < 16) g += gg;
            }
            const float excl = g - s0;         // groups strictly to the right
            const float be = Crow[r] + excl;
            float4 wv;
            wv.x = zf[r][0] * __expf(be + s0);
            wv.y = zf[r][1] * __expf(be + s1);
            wv.z = zf[r][2] * __expf(be + s2);
            wv.w = zf[r][3] * __expf(be + s3);
            Crow[r] += __shfl(g, grp0, 64);    // full row total from tj==0 lane
            *(float4*)&KWs[i0 + r][j0] = wv;
        }
        __syncthreads();

        // ---- GEMM2: O += W V  (thread computes O[i0..i0+3][d0..d0+3], d0=j0) ----
        #pragma unroll 2
        for (int j = 0; j < 64; j += 4) {
            float wrr[4][4], vss[4][4];
            #pragma unroll
            for (int r = 0; r < 4; ++r) {
                const float4 wv4 = *(const float4*)&KWs[i0 + r][j];
                UNPACK4(wrr[r], wv4);
            }
            #pragma unroll
            for (int s = 0; s < 4; ++s) {
                const float4 vv4 = *(const float4*)&Vs[j + s][j0];
                UNPACK4(vss[s], vv4);
            }
            #pragma unroll
            for (int r = 0; r < 4; ++r)
                #pragma unroll
                for (int c = 0; c < 4; ++c) {
                    float t0 = fmaf(wrr[r][0], vss[0][c], Of[r][c]);
                    t0 = fmaf(wrr[r][1], vss[1][c], t0);
                    t0 = fmaf(wrr[r][2], vss[2][c], t0);
                    Of[r][c] = fmaf(wrr[r][3], vss[3][c], t0);
                }
        }
    }

    // ---- epilogue ----
    #pragma unroll
    for (int r = 0; r < 4; ++r) {
        float4 ov;
        ov.x = Of[r][0]; ov.y = Of[r][1]; ov.z = Of[r][2]; ov.w = Of[r][3];
        *(float4*)(o + (i0 + r) * D_DIM + j0) = ov;
    }
}

extern "C" void kernel_launch(void* const* d_in, const int* in_sizes, int n_in,
                              void* d_out, int out_size, void* d_ws, size_t ws_size,
                              hipStream_t stream) {
    const float* q = (const float*)d_in[0];
    const float* k = (const float*)d_in[1];
    const float* v = (const float*)d_in[2];
    float* out = (float*)d_out;
    stickbreak_kernel<<<dim3(512), dim3(256), 0, stream>>>(q, k, v, out);
}

// Round 2
// 157.107 us; speedup vs baseline: 1.4224x; 1.4224x over previous
//
#include <hip/hip_runtime.h>
#include <hip/hip_bf16.h>
#include <math.h>

// Stickbreaking attention via bf16 MFMA, flash-style suffix-scan carry.
// B=2 H=16 S=1024 D=64.
//   GEMM1 (QK^T): split-precision bf16 (hi+lo residual), 3 MFMAs -> fp32-accurate logits.
//   GEMM2 (W V):  plain bf16 (W in [0,1], ~0.4% rel err -> well under 2% tolerance).
// Layouts: mfma_f32_16x16x32_bf16, A[m=lane&15][k=(lane>>4)*8+e], B[k=(lane>>4)*8+e][n=lane&15],
//          C/D col=lane&15, row=(lane>>4)*4+reg  (m89/m120-verified mappings).
// All LDS bf16 tiles use 72-elem (144 B) row pitch: b128 frag reads and staging writes
// are bank-uniform (verified by bank arithmetic: 36dw pitch -> 4j+m mod 32 uniform).

typedef __attribute__((ext_vector_type(8))) short short8;
typedef __attribute__((ext_vector_type(4))) short short4v;
typedef __attribute__((ext_vector_type(4))) float f32x4;

#define PITCH 72   // bf16 elems per LDS row: 144 B, 16B-aligned, conflict-free

__device__ inline short bf16r(float x) {
    __hip_bfloat16 h = __float2bfloat16(x);   // RNE
    return *(short*)&h;
}
__device__ inline float bf16f(short s) {
    union { unsigned u; float f; } c;
    c.u = ((unsigned)(unsigned short)s) << 16;
    return c.f;
}

__global__ __launch_bounds__(256, 2) void stickbreak_mfma(
    const float* __restrict__ Qg, const float* __restrict__ Kg,
    const float* __restrict__ Vg, float* __restrict__ Og)
{
    __shared__ __align__(16) short Qh[64 * PITCH];
    __shared__ __align__(16) short Ql[64 * PITCH];
    __shared__ __align__(16) short Kh[64 * PITCH];
    __shared__ __align__(16) short Kl[64 * PITCH];
    __shared__ __align__(16) short Vt[64 * PITCH];   // V transposed: Vt[d][j]
    __shared__ __align__(16) short Ws[64 * PITCH];   // W strip, [i][j]

    const int t = threadIdx.x;
    const int n = blockIdx.x;                 // 0..511
    // XCD swizzle: all 16 q-tiles of one (b,h) share n%8 -> same XCD L2 (K+V 512KB/head).
    const int bh = (n & 7) + ((n >> 7) << 3); // 0..31
    const int qt = (n >> 3) & 15;             // 0..15

    const size_t hbase = (size_t)bh * 1024 * 64;
    const float* qp = Qg + hbase + (size_t)qt * 64 * 64;
    const float* kp = Kg + hbase;
    const float* vp = Vg + hbase;
    float*       op = Og + hbase + (size_t)qt * 64 * 64;

    // staging maps
    const int srow = t >> 2;            // 0..63 (row)
    const int scol = (t & 3) << 4;      // 0/16/32/48 (col base, 16 floats per thread)
    const int vj   = (t & 15) << 2;     // j0 for V transpose (4x4 block)
    const int vd   = (t >> 4) << 2;     // d0

    // ---- stage Q hi/lo (once) ----
    {
        const float* src = qp + srow * 64 + scol;
        short8 h0, h1, l0, l1;
        #pragma unroll
        for (int i = 0; i < 16; i += 4) {
            const float4 f = *(const float4*)(src + i);
            float a[4] = {f.x, f.y, f.z, f.w};
            #pragma unroll
            for (int j = 0; j < 4; ++j) {
                const short hi = bf16r(a[j]);
                const short lo = bf16r(a[j] - bf16f(hi));
                const int idx = i + j;
                if (idx < 8) { h0[idx] = hi; l0[idx] = lo; }
                else         { h1[idx - 8] = hi; l1[idx - 8] = lo; }
            }
        }
        *(short8*)&Qh[srow * PITCH + scol]     = h0;
        *(short8*)&Qh[srow * PITCH + scol + 8] = h1;
        *(short8*)&Ql[srow * PITCH + scol]     = l0;
        *(short8*)&Ql[srow * PITCH + scol + 8] = l1;
    }

    const int lane = t & 63;
    const int wv   = t >> 6;      // wave 0..3 -> S/O rows [16wv,16wv+16)
    const int l16  = lane & 15;
    const int q4   = lane >> 4;   // quad 0..3

    f32x4 Oacc[4];
    #pragma unroll
    for (int i = 0; i < 4; ++i) Oacc[i] = (f32x4){0.f, 0.f, 0.f, 0.f};
    float Crow[4] = {0.f, 0.f, 0.f, 0.f};   // carried suffix sums (tiles right of current)

    for (int kt = qt; kt >= 0; --kt) {
        __syncthreads();   // previous iteration's GEMM2 done reading Kh/Kl/Vt

        // ---- stage K hi/lo ----
        {
            const float* src = kp + (size_t)kt * 4096 + srow * 64 + scol;
            short8 h0, h1, l0, l1;
            #pragma unroll
            for (int i = 0; i < 16; i += 4) {
                const float4 f = *(const float4*)(src + i);
                float a[4] = {f.x, f.y, f.z, f.w};
                #pragma unroll
                for (int j = 0; j < 4; ++j) {
                    const short hi = bf16r(a[j]);
                    const short lo = bf16r(a[j] - bf16f(hi));
                    const int idx = i + j;
                    if (idx < 8) { h0[idx] = hi; l0[idx] = lo; }
                    else         { h1[idx - 8] = hi; l1[idx - 8] = lo; }
                }
            }
            *(short8*)&Kh[srow * PITCH + scol]     = h0;
            *(short8*)&Kh[srow * PITCH + scol + 8] = h1;
            *(short8*)&Kl[srow * PITCH + scol]     = l0;
            *(short8*)&Kl[srow * PITCH + scol + 8] = l1;
        }
        // ---- stage V transposed (4x4 register-block transpose, b64 writes) ----
        {
            const float* src = vp + (size_t)kt * 4096;
            float rr[4][4];
            #pragma unroll
            for (int r = 0; r < 4; ++r) {
                const float4 f = *(const float4*)(src + (vj + r) * 64 + vd);
                rr[r][0] = f.x; rr[r][1] = f.y; rr[r][2] = f.z; rr[r][3] = f.w;
            }
            #pragma unroll
            for (int x = 0; x < 4; ++x) {
                short4v w4;
                #pragma unroll
                for (int r = 0; r < 4; ++r) w4[r] = bf16r(rr[r][x]);
                *(short4v*)&Vt[(vd + x) * PITCH + vj] = w4;
            }
        }
        __syncthreads();

        // ---- GEMM1: S = Q K^T (split precision, 3 MFMAs) ----
        f32x4 Sacc[4];
        #pragma unroll
        for (int i = 0; i < 4; ++i) Sacc[i] = (f32x4){0.f, 0.f, 0.f, 0.f};
        #pragma unroll
        for (int ks = 0; ks < 2; ++ks) {
            const short8 ah = *(const short8*)&Qh[(16 * wv + l16) * PITCH + 32 * ks + 8 * q4];
            const short8 al = *(const short8*)&Ql[(16 * wv + l16) * PITCH + 32 * ks + 8 * q4];
            #pragma unroll
            for (int nt = 0; nt < 4; ++nt) {
                const short8 bh_ = *(const short8*)&Kh[(16 * nt + l16) * PITCH + 32 * ks + 8 * q4];
                const short8 bl_ = *(const short8*)&Kl[(16 * nt + l16) * PITCH + 32 * ks + 8 * q4];
                Sacc[nt] = __builtin_amdgcn_mfma_f32_16x16x32_bf16(ah, bh_, Sacc[nt], 0, 0, 0);
                Sacc[nt] = __builtin_amdgcn_mfma_f32_16x16x32_bf16(ah, bl_, Sacc[nt], 0, 0, 0);
                Sacc[nt] = __builtin_amdgcn_mfma_f32_16x16x32_bf16(al, bh_, Sacc[nt], 0, 0, 0);
            }
        }

        // ---- sigmoid / log-sigmoid, causal mask on diagonal tile ----
        const bool diag = (kt == qt);
        const int rowin = 16 * wv + 4 * q4;   // + r = row within 64-q-tile
        float zv[4][4], lb[4][4];
        #pragma unroll
        for (int nt = 0; nt < 4; ++nt) {
            #pragma unroll
            for (int r = 0; r < 4; ++r) {
                const float l  = Sacc[nt][r] * 0.125f;
                const float e  = __expf(-fabsf(l));
                const float rc = 1.0f / (1.0f + e);
                float z  = (l >= 0.f) ? rc : e * rc;              // sigmoid(l)
                float lv = -(fmaxf(l, 0.f) + __logf(1.0f + e));   // -softplus(l)
                if (diag && (16 * nt + l16 > rowin + r)) { z = 0.f; lv = 0.f; }
                zv[nt][r] = z;
                lb[nt][r] = lv;
            }
        }

        // ---- suffix scan along j (16-lane butterflies + group totals) + weights ----
        float wgt[4][4];
        #pragma unroll
        for (int r = 0; r < 4; ++r) {
            float st[4], T[4];
            #pragma unroll
            for (int nt = 0; nt < 4; ++nt) {
                float g = lb[nt][r];
                #pragma unroll
                for (int off = 1; off < 16; off <<= 1) {
                    const float gg = __shfl_down(g, off, 64);
                    if (l16 + off < 16) g += gg;
                }
                st[nt] = g;                          // inclusive suffix within 16-group
                T[nt]  = __shfl(g, lane & 48, 64);   // group total (from l16==0 lane)
            }
            float tsuf = 0.f;
            #pragma unroll
            for (int nt = 3; nt >= 0; --nt) {
                wgt[nt][r] = zv[nt][r] * __expf(Crow[r] + st[nt] + tsuf);
                tsuf += T[nt];
            }
            Crow[r] += tsuf;   // whole 64-tile row total
        }

        // ---- write W strip (C-layout -> natural [i][j] in LDS, bf16) ----
        #pragma unroll
        for (int nt = 0; nt < 4; ++nt)
            #pragma unroll
            for (int r = 0; r < 4; ++r)
                Ws[(rowin + r) * PITCH + 16 * nt + l16] = bf16r(wgt[nt][r]);

        __syncthreads();   // safety: Ws visible before A-frag reads

        // ---- GEMM2: O += W V ----
        #pragma unroll
        for (int ks = 0; ks < 2; ++ks) {
            const short8 wa = *(const short8*)&Ws[(16 * wv + l16) * PITCH + 32 * ks + 8 * q4];
            #pragma unroll
            for (int dt = 0; dt < 4; ++dt) {
                const short8 vb = *(const short8*)&Vt[(16 * dt + l16) * PITCH + 32 * ks + 8 * q4];
                Oacc[dt] = __builtin_amdgcn_mfma_f32_16x16x32_bf16(wa, vb, Oacc[dt], 0, 0, 0);
            }
        }
    }

    // ---- epilogue: C-layout scatter to global (fp32) ----
    #pragma unroll
    for (int dt = 0; dt < 4; ++dt)
        #pragma unroll
        for (int r = 0; r < 4; ++r)
            op[(16 * wv + 4 * q4 + r) * 64 + 16 * dt + l16] = Oacc[dt][r];
}

extern "C" void kernel_launch(void* const* d_in, const int* in_sizes, int n_in,
                              void* d_out, int out_size, void* d_ws, size_t ws_size,
                              hipStream_t stream) {
    const float* q = (const float*)d_in[0];
    const float* k = (const float*)d_in[1];
    const float* v = (const float*)d_in[2];
    float* out = (float*)d_out;
    stickbreak_mfma<<<dim3(512), dim3(256), 0, stream>>>(q, k, v, out);
}

// Round 3
// 149.487 us; speedup vs baseline: 1.4949x; 1.0510x over previous
//
#include <hip/hip_runtime.h>
#include <hip/hip_bf16.h>
#include <math.h>

// Stickbreaking attention via bf16 MFMA, flash-style suffix-scan carry.
// B=2 H=16 S=1024 D=64.
// Round-3 changes vs round-2:
//  * complementary length pairing: block c and c+256 get qt and 15-qt, so under
//    round-robin placement every CU's two blocks sum to 17 work-units (was: same
//    qt twice -> 2x makespan, the 10.8% occupancy smoking gun).
//  * Q fragments held in registers (Q is loop-invariant per block): removes
//    Qh/Ql LDS (55->36.9 KB -> 4 blocks/CU capacity) and the Q staging pass.
//  * per-row elementwise/scan restructure cuts live VGPRs -> launch_bounds(256,4).
// GEMM1 split-precision bf16 (hi+lo residual, 3 MFMAs -> fp32-accurate logits);
// GEMM2 plain bf16. mfma_f32_16x16x32_bf16 layouts per m89/m120.

typedef __attribute__((ext_vector_type(8))) short short8;
typedef __attribute__((ext_vector_type(4))) short short4v;
typedef __attribute__((ext_vector_type(4))) float f32x4;

#define PITCH 72   // bf16 elems per LDS row: 144 B, 16B-aligned, bank-uniform for b128

__device__ inline short bf16r(float x) {
    __hip_bfloat16 h = __float2bfloat16(x);   // RNE
    return *(short*)&h;
}
__device__ inline float bf16f(short s) {
    union { unsigned u; float f; } c;
    c.u = ((unsigned)(unsigned short)s) << 16;
    return c.f;
}

__global__ __launch_bounds__(256, 4) void stickbreak_mfma(
    const float* __restrict__ Qg, const float* __restrict__ Kg,
    const float* __restrict__ Vg, float* __restrict__ Og)
{
    __shared__ __align__(16) short Kh[64 * PITCH];
    __shared__ __align__(16) short Kl[64 * PITCH];
    __shared__ __align__(16) short Vt[64 * PITCH];   // V transposed: Vt[d][j]
    __shared__ __align__(16) short Ws[64 * PITCH];   // W strip, [i][j]

    const int t = threadIdx.x;
    const int n = blockIdx.x;                 // 0..511
    // bh: n&7 fastest -> all 16 q-tiles of one head share an XCD slot (K/V L2 reuse).
    const int bh = (n & 7) + 8 * (n >> 7);    // 0..31
    const int qr = (n >> 3) & 15;
    const int qt = (n >> 8) ? (15 - qr) : qr; // complementary pairing c <-> c+256

    const size_t hbase = (size_t)bh * 1024 * 64;
    const float* qp = Qg + hbase + (size_t)qt * 64 * 64;
    const float* kp = Kg + hbase;
    const float* vp = Vg + hbase;
    float*       op = Og + hbase + (size_t)qt * 64 * 64;

    const int lane = t & 63;
    const int wv   = t >> 6;      // wave 0..3 -> rows [16wv, 16wv+16)
    const int l16  = lane & 15;
    const int q4   = lane >> 4;   // quad 0..3

    // staging maps (K hi/lo: 16 floats/thread; V transpose: 4x4 register block)
    const int srow = t >> 2;            // 0..63
    const int scol = (t & 3) << 4;      // 0/16/32/48
    const int vj   = (t & 15) << 2;
    const int vd   = (t >> 4) << 2;

    // ---- Q fragments straight to registers (loop-invariant) ----
    short8 qfh[2], qfl[2];
    {
        const float* qrow = qp + (16 * wv + l16) * 64;
        #pragma unroll
        for (int ks = 0; ks < 2; ++ks) {
            const int base = 32 * ks + 8 * q4;
            const float4 f0 = *(const float4*)(qrow + base);
            const float4 f1 = *(const float4*)(qrow + base + 4);
            float a[8] = {f0.x, f0.y, f0.z, f0.w, f1.x, f1.y, f1.z, f1.w};
            #pragma unroll
            for (int j = 0; j < 8; ++j) {
                const short hi = bf16r(a[j]);
                qfh[ks][j] = hi;
                qfl[ks][j] = bf16r(a[j] - bf16f(hi));
            }
        }
    }

    f32x4 Oacc[4];
    #pragma unroll
    for (int i = 0; i < 4; ++i) Oacc[i] = (f32x4){0.f, 0.f, 0.f, 0.f};
    float Crow[4] = {0.f, 0.f, 0.f, 0.f};   // carried suffix sums (tiles right of current)

    for (int kt = qt; kt >= 0; --kt) {
        __syncthreads();   // previous iteration's GEMM2 done reading Vt/Ws

        // ---- stage K hi/lo ----
        {
            const float* src = kp + (size_t)kt * 4096 + srow * 64 + scol;
            short8 h0, h1, l0, l1;
            #pragma unroll
            for (int i = 0; i < 16; i += 4) {
                const float4 f = *(const float4*)(src + i);
                float a[4] = {f.x, f.y, f.z, f.w};
                #pragma unroll
                for (int j = 0; j < 4; ++j) {
                    const short hi = bf16r(a[j]);
                    const short lo = bf16r(a[j] - bf16f(hi));
                    const int idx = i + j;
                    if (idx < 8) { h0[idx] = hi; l0[idx] = lo; }
                    else         { h1[idx - 8] = hi; l1[idx - 8] = lo; }
                }
            }
            *(short8*)&Kh[srow * PITCH + scol]     = h0;
            *(short8*)&Kh[srow * PITCH + scol + 8] = h1;
            *(short8*)&Kl[srow * PITCH + scol]     = l0;
            *(short8*)&Kl[srow * PITCH + scol + 8] = l1;
        }
        // ---- stage V transposed ----
        {
            const float* src = vp + (size_t)kt * 4096;
            float rr[4][4];
            #pragma unroll
            for (int r = 0; r < 4; ++r) {
                const float4 f = *(const float4*)(src + (vj + r) * 64 + vd);
                rr[r][0] = f.x; rr[r][1] = f.y; rr[r][2] = f.z; rr[r][3] = f.w;
            }
            #pragma unroll
            for (int x = 0; x < 4; ++x) {
                short4v w4;
                #pragma unroll
                for (int r = 0; r < 4; ++r) w4[r] = bf16r(rr[r][x]);
                *(short4v*)&Vt[(vd + x) * PITCH + vj] = w4;
            }
        }
        __syncthreads();

        // ---- GEMM1: S = Q K^T (split precision, 3 MFMAs per frag pair) ----
        f32x4 Sacc[4];
        #pragma unroll
        for (int i = 0; i < 4; ++i) Sacc[i] = (f32x4){0.f, 0.f, 0.f, 0.f};
        #pragma unroll
        for (int ks = 0; ks < 2; ++ks) {
            #pragma unroll
            for (int nt = 0; nt < 4; ++nt) {
                const short8 bh_ = *(const short8*)&Kh[(16 * nt + l16) * PITCH + 32 * ks + 8 * q4];
                const short8 bl_ = *(const short8*)&Kl[(16 * nt + l16) * PITCH + 32 * ks + 8 * q4];
                Sacc[nt] = __builtin_amdgcn_mfma_f32_16x16x32_bf16(qfh[ks], bh_, Sacc[nt], 0, 0, 0);
                Sacc[nt] = __builtin_amdgcn_mfma_f32_16x16x32_bf16(qfh[ks], bl_, Sacc[nt], 0, 0, 0);
                Sacc[nt] = __builtin_amdgcn_mfma_f32_16x16x32_bf16(qfl[ks], bh_, Sacc[nt], 0, 0, 0);
            }
        }

        // ---- per-row: sigmoid/log-sigmoid, mask, suffix scan, weights, Ws write ----
        const bool diag = (kt == qt);
        #pragma unroll
        for (int r = 0; r < 4; ++r) {
            const int irow = 16 * wv + 4 * q4 + r;   // row within the 64-row q-tile
            float z4[4], lb4[4];
            #pragma unroll
            for (int nt = 0; nt < 4; ++nt) {
                const float l  = Sacc[nt][r] * 0.125f;
                const float e  = __expf(-fabsf(l));
                const float rc = 1.0f / (1.0f + e);
                float z  = (l >= 0.f) ? rc : e * rc;              // sigmoid(l)
                float lv = -(fmaxf(l, 0.f) + __logf(1.0f + e));   // -softplus(l)
                if (diag && (16 * nt + l16 > irow)) { z = 0.f; lv = 0.f; }
                z4[nt] = z; lb4[nt] = lv;
            }
            float st[4], T[4];
            #pragma unroll
            for (int nt = 0; nt < 4; ++nt) {
                float g = lb4[nt];
                #pragma unroll
                for (int off = 1; off < 16; off <<= 1) {
                    const float gg = __shfl_down(g, off, 64);
                    if (l16 + off < 16) g += gg;
                }
                st[nt] = g;                          // inclusive suffix within 16-group
                T[nt]  = __shfl(g, lane & 48, 64);   // group total
            }
            float tsuf = 0.f;
            #pragma unroll
            for (int nt = 3; nt >= 0; --nt) {
                const float w = z4[nt] * __expf(Crow[r] + st[nt] + tsuf);
                tsuf += T[nt];
                Ws[irow * PITCH + 16 * nt + l16] = bf16r(w);
            }
            Crow[r] += tsuf;
        }

        __syncthreads();   // Ws visible before A-frag reads

        // ---- GEMM2: O += W V ----
        #pragma unroll
        for (int ks = 0; ks < 2; ++ks) {
            const short8 wa = *(const short8*)&Ws[(16 * wv + l16) * PITCH + 32 * ks + 8 * q4];
            #pragma unroll
            for (int dt = 0; dt < 4; ++dt) {
                const short8 vb = *(const short8*)&Vt[(16 * dt + l16) * PITCH + 32 * ks + 8 * q4];
                Oacc[dt] = __builtin_amdgcn_mfma_f32_16x16x32_bf16(wa, vb, Oacc[dt], 0, 0, 0);
            }
        }
    }

    // ---- epilogue: C-layout scatter to global (fp32) ----
    #pragma unroll
    for (int dt = 0; dt < 4; ++dt)
        #pragma unroll
        for (int r = 0; r < 4; ++r)
            op[(16 * wv + 4 * q4 + r) * 64 + 16 * dt + l16] = Oacc[dt][r];
}

extern "C" void kernel_launch(void* const* d_in, const int* in_sizes, int n_in,
                              void* d_out, int out_size, void* d_ws, size_t ws_size,
                              hipStream_t stream) {
    const float* q = (const float*)d_in[0];
    const float* k = (const float*)d_in[1];
    const float* v = (const float*)d_in[2];
    float* out = (float*)d_out;
    stickbreak_mfma<<<dim3(512), dim3(256), 0, stream>>>(q, k, v, out);
}

// Round 4
// 105.457 us; speedup vs baseline: 2.1190x; 1.4175x over previous
//
#include <hip/hip_runtime.h>
#include <hip/hip_bf16.h>
#include <math.h>

// Stickbreaking attention via bf16 MFMA, flash-style suffix-scan carry.
// B=2 H=16 S=1024 D=64.
// Round-4 changes vs round-3 (which was latency-bound at ~12.5K cyc/iteration,
// ~10K of it in 80 dependent ds_bpermute shuffles of the per-row suffix scan):
//  * GEMM1 computes S^T (swap MFMA operands; A-frag-of-Q == B-frag-of-Q^T in
//    registers, so the swap is free). In S^T's C-layout each lane holds a FIXED
//    query row (i=l16) and 16 j-values -> suffix scan = in-register adds +
//    12 shuffles total (depth 3, 4-way ILP), vs 80 depth-heavy ones.
//  * sigmoid fused into exponent: w = exp(l + lb + suffix + Crow) since
//    sigmoid(l) = e^{l+lb}; causal mask is just the sentinel l = -1e30.
//  * Ws written as packed b64 (4 writes vs 16 b16 scalars).
//  * next K/V tile prefetched into registers after the staging barrier
//    (global latency hidden behind GEMM1/scan/GEMM2).
// GEMM1 split-precision bf16 (hi+lo residual, 3 MFMAs -> fp32-accurate logits);
// GEMM2 plain bf16. mfma_f32_16x16x32_bf16 layouts per m89/m120:
//   A[m=lane&15][k=(lane>>4)*8+e], B[k][n=lane&15], C/D col=lane&15, row=(lane>>4)*4+reg.

typedef __attribute__((ext_vector_type(8))) short short8;
typedef __attribute__((ext_vector_type(4))) short short4v;
typedef __attribute__((ext_vector_type(4))) float f32x4;

#define PITCH 72   // bf16 elems per LDS row: 144 B, 16B-aligned, bank-uniform for b128

__device__ inline short bf16r(float x) {
    __hip_bfloat16 h = __float2bfloat16(x);   // RNE
    return *(short*)&h;
}
__device__ inline float bf16f(short s) {
    union { unsigned u; float f; } c;
    c.u = ((unsigned)(unsigned short)s) << 16;
    return c.f;
}

__global__ __launch_bounds__(256, 2) void stickbreak_mfma(
    const float* __restrict__ Qg, const float* __restrict__ Kg,
    const float* __restrict__ Vg, float* __restrict__ Og)
{
    __shared__ __align__(16) short Kh[64 * PITCH];
    __shared__ __align__(16) short Kl[64 * PITCH];
    __shared__ __align__(16) short Vt[64 * PITCH];   // V transposed: Vt[d][j]
    __shared__ __align__(16) short Ws[64 * PITCH];   // W strip, [i][j]

    const int t = threadIdx.x;
    const int n = blockIdx.x;                 // 0..511
    // n&7 fastest -> all 16 q-tiles of one head share an XCD slot (K/V L2 reuse).
    const int bh = (n & 7) + 8 * (n >> 7);    // 0..31
    const int qr = (n >> 3) & 15;
    const int qt = (n >> 8) ? (15 - qr) : qr; // complementary pairing c <-> c+256

    const size_t hbase = (size_t)bh * 1024 * 64;
    const float* qp = Qg + hbase + (size_t)qt * 64 * 64;
    const float* kp = Kg + hbase;
    const float* vp = Vg + hbase;
    float*       op = Og + hbase + (size_t)qt * 64 * 64;

    const int lane = t & 63;
    const int wv   = t >> 6;      // wave 0..3 -> q-rows [16wv, 16wv+16)
    const int l16  = lane & 15;
    const int q4   = lane >> 4;   // quad 0..3

    // staging maps (K: 16 floats/thread; V transpose: 4x4 register block)
    const int srow = t >> 2;            // 0..63
    const int scol = (t & 3) << 4;      // 0/16/32/48
    const int vj   = (t & 15) << 2;
    const int vd   = (t >> 4) << 2;

    // ---- Q fragments straight to registers (loop-invariant) ----
    short8 qfh[2], qfl[2];
    {
        const float* qrow = qp + (16 * wv + l16) * 64;
        #pragma unroll
        for (int ks = 0; ks < 2; ++ks) {
            const int base = 32 * ks + 8 * q4;
            const float4 f0 = *(const float4*)(qrow + base);
            const float4 f1 = *(const float4*)(qrow + base + 4);
            float a[8] = {f0.x, f0.y, f0.z, f0.w, f1.x, f1.y, f1.z, f1.w};
            #pragma unroll
            for (int j = 0; j < 8; ++j) {
                const short hi = bf16r(a[j]);
                qfh[ks][j] = hi;
                qfl[ks][j] = bf16r(a[j] - bf16f(hi));
            }
        }
    }

    f32x4 Oacc[4];
    #pragma unroll
    for (int i = 0; i < 4; ++i) Oacc[i] = (f32x4){0.f, 0.f, 0.f, 0.f};
    float Crow = 0.f;    // carried suffix sum for row 16wv+l16 (replicated over q4)

    // ---- prefetch first K/V tile into registers ----
    float4 kreg[4], vreg[4];
    {
        const float* ksrc = kp + (size_t)qt * 4096 + srow * 64 + scol;
        const float* vsrc = vp + (size_t)qt * 4096;
        #pragma unroll
        for (int i = 0; i < 4; ++i) kreg[i] = *(const float4*)(ksrc + 4 * i);
        #pragma unroll
        for (int r = 0; r < 4; ++r) vreg[r] = *(const float4*)(vsrc + (vj + r) * 64 + vd);
    }

    for (int kt = qt; kt >= 0; --kt) {
        // ---- stage K hi/lo from prefetched registers ----
        {
            short8 h0, h1, l0, l1;
            #pragma unroll
            for (int i = 0; i < 4; ++i) {
                float a[4] = {kreg[i].x, kreg[i].y, kreg[i].z, kreg[i].w};
                #pragma unroll
                for (int j = 0; j < 4; ++j) {
                    const short hi = bf16r(a[j]);
                    const short lo = bf16r(a[j] - bf16f(hi));
                    const int idx = 4 * i + j;
                    if (idx < 8) { h0[idx] = hi; l0[idx] = lo; }
                    else         { h1[idx - 8] = hi; l1[idx - 8] = lo; }
                }
            }
            *(short8*)&Kh[srow * PITCH + scol]     = h0;
            *(short8*)&Kh[srow * PITCH + scol + 8] = h1;
            *(short8*)&Kl[srow * PITCH + scol]     = l0;
            *(short8*)&Kl[srow * PITCH + scol + 8] = l1;
        }
        // ---- stage V transposed from prefetched registers ----
        {
            #pragma unroll
            for (int x = 0; x < 4; ++x) {
                float rr[4] = { x == 0 ? vreg[0].x : x == 1 ? vreg[0].y : x == 2 ? vreg[0].z : vreg[0].w,
                                x == 0 ? vreg[1].x : x == 1 ? vreg[1].y : x == 2 ? vreg[1].z : vreg[1].w,
                                x == 0 ? vreg[2].x : x == 1 ? vreg[2].y : x == 2 ? vreg[2].z : vreg[2].w,
                                x == 0 ? vreg[3].x : x == 1 ? vreg[3].y : x == 2 ? vreg[3].z : vreg[3].w };
                short4v w4;
                #pragma unroll
                for (int r = 0; r < 4; ++r) w4[r] = bf16r(rr[r]);
                *(short4v*)&Vt[(vd + x) * PITCH + vj] = w4;
            }
        }
        __syncthreads();

        // ---- prefetch next tile (overlaps GEMM1/scan/GEMM2) ----
        if (kt > 0) {
            const float* ksrc = kp + (size_t)(kt - 1) * 4096 + srow * 64 + scol;
            const float* vsrc = vp + (size_t)(kt - 1) * 4096;
            #pragma unroll
            for (int i = 0; i < 4; ++i) kreg[i] = *(const float4*)(ksrc + 4 * i);
            #pragma unroll
            for (int r = 0; r < 4; ++r) vreg[r] = *(const float4*)(vsrc + (vj + r) * 64 + vd);
        }

        // ---- GEMM1: S^T = K Q^T (split precision, 3 MFMAs per frag pair) ----
        // D[m=j][n=i]: col i = l16, row j = 16nt + 4q4 + reg.
        f32x4 Sacc[4];
        #pragma unroll
        for (int i = 0; i < 4; ++i) Sacc[i] = (f32x4){0.f, 0.f, 0.f, 0.f};
        #pragma unroll
        for (int ks = 0; ks < 2; ++ks) {
            #pragma unroll
            for (int nt = 0; nt < 4; ++nt) {
                const short8 ah = *(const short8*)&Kh[(16 * nt + l16) * PITCH + 32 * ks + 8 * q4];
                const short8 al = *(const short8*)&Kl[(16 * nt + l16) * PITCH + 32 * ks + 8 * q4];
                Sacc[nt] = __builtin_amdgcn_mfma_f32_16x16x32_bf16(ah, qfh[ks], Sacc[nt], 0, 0, 0);
                Sacc[nt] = __builtin_amdgcn_mfma_f32_16x16x32_bf16(al, qfh[ks], Sacc[nt], 0, 0, 0);
                Sacc[nt] = __builtin_amdgcn_mfma_f32_16x16x32_bf16(ah, qfl[ks], Sacc[nt], 0, 0, 0);
            }
        }

        // ---- elementwise + suffix scan (lane owns row i=16wv+l16, j = 16nt+4q4+reg) ----
        const bool diag = (kt == qt);
        const int irow = 16 * wv + l16;          // row within 64-row q-tile
        float ex[4][4];                          // l + lb + in-run inclusive suffix
        float sR[4];                             // run totals
        #pragma unroll
        for (int nt = 0; nt < 4; ++nt) {
            float lbr[4], lv[4];
            #pragma unroll
            for (int reg = 0; reg < 4; ++reg) {
                float l = Sacc[nt][reg] * 0.125f;
                if (diag && (16 * nt + 4 * q4 + reg > irow)) l = -1e30f;  // mask sentinel
                const float e  = __expf(-fabsf(l));
                const float lb = -(fmaxf(l, 0.f) + __logf(1.f + e));     // -softplus(l)
                lv[reg] = l; lbr[reg] = lb;
            }
            const float s3 = lbr[3];
            const float s2 = lbr[2] + s3;
            const float s1 = lbr[1] + s2;
            const float s0 = lbr[0] + s1;        // inclusive suffix within run
            ex[nt][0] = lv[0] + lbr[0] + s0;
            ex[nt][1] = lv[1] + lbr[1] + s1;
            ex[nt][2] = lv[2] + lbr[2] + s2;
            ex[nt][3] = lv[3] + lbr[3] + s3;
            sR[nt] = s0;
        }
        // cross-lane inclusive suffix over q4 (stride-16 lanes), then over nt
        float gq[4], Tn[4];
        #pragma unroll
        for (int nt = 0; nt < 4; ++nt) {
            float g = sR[nt];
            float u = __shfl_down(g, 16, 64); if (q4 < 3) g += u;
            u = __shfl_down(g, 32, 64);       if (q4 < 2) g += u;
            gq[nt] = g;                          // sum over q4' >= q4 within nt
            Tn[nt] = __shfl(g, l16, 64);         // nt total (from q4=0 lane of same i)
        }
        const float TSa[4] = { Tn[1] + Tn[2] + Tn[3], Tn[2] + Tn[3], Tn[3], 0.f };
        #pragma unroll
        for (int nt = 0; nt < 4; ++nt) {
            const float cross = (gq[nt] - sR[nt]) + TSa[nt] + Crow;
            short4v w4;
            #pragma unroll
            for (int reg = 0; reg < 4; ++reg)
                w4[reg] = bf16r(__expf(ex[nt][reg] + cross));
            *(short4v*)&Ws[irow * PITCH + 16 * nt + 4 * q4] = w4;
        }
        Crow += TSa[0] + Tn[0];

        __syncthreads();   // Ws/Vt coherent before GEMM2 frag reads

        // ---- GEMM2: O += W V ----
        #pragma unroll
        for (int ks = 0; ks < 2; ++ks) {
            const short8 wa = *(const short8*)&Ws[(16 * wv + l16) * PITCH + 32 * ks + 8 * q4];
            #pragma unroll
            for (int dt = 0; dt < 4; ++dt) {
                const short8 vb = *(const short8*)&Vt[(16 * dt + l16) * PITCH + 32 * ks + 8 * q4];
                Oacc[dt] = __builtin_amdgcn_mfma_f32_16x16x32_bf16(wa, vb, Oacc[dt], 0, 0, 0);
            }
        }

        __syncthreads();   // GEMM1/GEMM2 LDS reads done before next staging overwrites
    }

    // ---- epilogue: C-layout scatter to global (fp32) ----
    #pragma unroll
    for (int dt = 0; dt < 4; ++dt)
        #pragma unroll
        for (int r = 0; r < 4; ++r)
            op[(16 * wv + 4 * q4 + r) * 64 + 16 * dt + l16] = Oacc[dt][r];
}

extern "C" void kernel_launch(void* const* d_in, const int* in_sizes, int n_in,
                              void* d_out, int out_size, void* d_ws, size_t ws_size,
                              hipStream_t stream) {
    const float* q = (const float*)d_in[0];
    const float* k = (const float*)d_in[1];
    const float* v = (const float*)d_in[2];
    float* out = (float*)d_out;
    stickbreak_mfma<<<dim3(512), dim3(256), 0, stream>>>(q, k, v, out);
}